// Round 1
// baseline (2357.303 us; speedup 1.0000x reference)
//
#include <hip/hip_runtime.h>
#include <cstdint>
#include <cstddef>

// Problem constants (from reference)
#define BATCH 4096
#define NCH 10
#define FEAT 2048
#define NOUT 2048
#define MROWS (BATCH * NCH)   // 40960
#define KP 6144               // 3*FEAT for bf16x3 split GEMM
#define BN_EPS 1e-3f

using u16 = unsigned short;
typedef __attribute__((ext_vector_type(8))) short bf16x8;
typedef __attribute__((ext_vector_type(4))) float f32x4;

// ---------- bf16 split helpers (manual RNE, no hip_bf16 API dependency) ----------
__device__ __forceinline__ u16 f2bf(float f) {
  uint32_t u = __float_as_uint(f);
  u += 0x7FFFu + ((u >> 16) & 1u);   // round-to-nearest-even
  return (u16)(u >> 16);
}
__device__ __forceinline__ float bf2f(u16 h) {
  return __uint_as_float(((uint32_t)h) << 16);
}

// ---------- async global->LDS, 16B per lane ----------
__device__ __forceinline__ void gload16(const u16* g, u16* l) {
  __builtin_amdgcn_global_load_lds(
      (const __attribute__((address_space(1))) void*)g,
      (__attribute__((address_space(3))) void*)l, 16, 0, 0);
}

// ---------- prep: norm_adj (10x10) + BN scale/shift ----------
__global__ void prep_small_kernel(const float* __restrict__ adj,
                                  const float* __restrict__ gamma,
                                  const float* __restrict__ beta,
                                  const float* __restrict__ mean,
                                  const float* __restrict__ var,
                                  float* __restrict__ adjn,
                                  float* __restrict__ sb, float* __restrict__ tb) {
  int tid = blockIdx.x * 256 + threadIdx.x;
  if (tid < NOUT) {
    float sv = gamma[tid] * rsqrtf(var[tid] + BN_EPS);
    sb[tid] = sv;
    tb[tid] = beta[tid] - mean[tid] * sv;
  }
  if (tid < NCH * NCH) {
    int i = tid / NCH, j = tid % NCH;
    float di = 0.f, dj = 0.f;
    for (int q = 0; q < NCH; ++q) {
      di += fabsf(adj[i * NCH + q]);
      dj += fabsf(adj[j * NCH + q]);
    }
    di = fmaxf(di, 1e-8f);
    dj = fmaxf(dj, 1e-8f);
    adjn[tid] = adj[i * NCH + j] * rsqrtf(di * dj) + (i == j ? 1.f : 0.f);
  }
}

// ---------- prep: transpose W [K][N] fp32 -> Bt [N][KP] bf16 (hi, hi, lo segments) ----------
__global__ void prep_b_kernel(const float* __restrict__ W, u16* __restrict__ bt) {
  __shared__ float tile[32][33];
  int tx = threadIdx.x, ty = threadIdx.y;     // 32 x 8
  int n0 = blockIdx.x * 32, k0 = blockIdx.y * 32;
#pragma unroll
  for (int r = 0; r < 4; ++r)
    tile[ty + 8 * r][tx] = W[(size_t)(k0 + ty + 8 * r) * NOUT + n0 + tx];
  __syncthreads();
#pragma unroll
  for (int r = 0; r < 4; ++r) {
    int n = n0 + ty + 8 * r;
    int k = k0 + tx;
    float v = tile[tx][ty + 8 * r];
    u16 hi = f2bf(v);
    u16 lo = f2bf(v - bf2f(hi));
    size_t base = (size_t)n * KP;
    bt[base + k] = hi;            // seg0: paired with xm_hi
    bt[base + 2048 + k] = hi;     // seg1: paired with xm_lo
    bt[base + 4096 + k] = lo;     // seg2: paired with xm_hi
  }
}

// ---------- premix: xm[b][i][f] = sum_j adjn[i][j] * x[b][j][f], split to hi/lo bf16 ----------
__global__ void premix_kernel(const float* __restrict__ x, const float* __restrict__ adjn,
                              u16* __restrict__ xh, u16* __restrict__ xl) {
  __shared__ float A[NCH * NCH];
  int t = threadIdx.x;
  if (t < NCH * NCH) A[t] = adjn[t];
  __syncthreads();
  int b = blockIdx.x;
  const float* xb = x + (size_t)b * (NCH * FEAT);
  u16* xhb = xh + (size_t)b * (NCH * FEAT);
  u16* xlb = xl + (size_t)b * (NCH * FEAT);
  for (int f4 = t; f4 < FEAT / 4; f4 += 256) {
    float4 v[NCH];
#pragma unroll
    for (int j = 0; j < NCH; ++j) v[j] = ((const float4*)(xb + j * FEAT))[f4];
#pragma unroll
    for (int i = 0; i < NCH; ++i) {
      float ox = 0.f, oy = 0.f, oz = 0.f, ow = 0.f;
#pragma unroll
      for (int j = 0; j < NCH; ++j) {
        float a = A[i * NCH + j];
        ox = fmaf(a, v[j].x, ox);
        oy = fmaf(a, v[j].y, oy);
        oz = fmaf(a, v[j].z, oz);
        ow = fmaf(a, v[j].w, ow);
      }
      u16 hx = f2bf(ox), hy = f2bf(oy), hz = f2bf(oz), hw = f2bf(ow);
      ushort4 hv = make_ushort4(hx, hy, hz, hw);
      ushort4 lv = make_ushort4(f2bf(ox - bf2f(hx)), f2bf(oy - bf2f(hy)),
                                f2bf(oz - bf2f(hz)), f2bf(ow - bf2f(hw)));
      ((ushort4*)(xhb + i * FEAT))[f4] = hv;
      ((ushort4*)(xlb + i * FEAT))[f4] = lv;
    }
  }
}

// ---------- main GEMM: [40960 x 6144] x [6144 x 2048] bf16 -> fp32, fused epilogue ----------
// m97 structure: 128x128 tile, BK=64, 4 waves (2x2), global_load_lds w16, 2-barrier K-loop.
__global__ void __launch_bounds__(256) gemm_kernel(
    const u16* __restrict__ xh, const u16* __restrict__ xl,
    const u16* __restrict__ bt, const float* __restrict__ bias,
    const float* __restrict__ sb, const float* __restrict__ tb,
    float* __restrict__ out) {
  __shared__ __align__(16) u16 As[128 * 64];
  __shared__ __align__(16) u16 Bs[128 * 64];
  const int tid = threadIdx.x;
  const int w = tid >> 6, l = tid & 63;
  const int wr = w >> 1, wc = w & 1;             // wave -> 64x64 quadrant
  const int m0 = blockIdx.y * 128, n0 = blockIdx.x * 128;
  const int srow = w * 8 + (l >> 3);             // staging row within 32-row group
  const int scol = (l & 7) * 8;                  // ushort offset (16B chunk) within row
  const int l15 = l & 15;
  const int kgrp = (l >> 4) * 8;                 // k element offset within fragment

  f32x4 acc[4][4];
#pragma unroll
  for (int i = 0; i < 4; ++i)
#pragma unroll
    for (int j = 0; j < 4; ++j) acc[i][j] = (f32x4){0.f, 0.f, 0.f, 0.f};

  for (int kk = 0; kk < KP / 64; ++kk) {         // 96 K-steps
    // segment select: seg0 -> xm_hi, seg1 -> xm_lo, seg2 -> xm_hi
    const u16* Ab = (kk >= 32 && kk < 64) ? xl : xh;
    const int ak = (kk & 31) * 64;               // element offset within 2048-K array
    __syncthreads();                             // prev compute done before overwrite
#pragma unroll
    for (int i = 0; i < 4; ++i) {
      const u16* g = Ab + (size_t)(m0 + i * 32 + srow) * FEAT + ak + scol;
      gload16(g, &As[i * 2048 + w * 512]);
    }
#pragma unroll
    for (int i = 0; i < 4; ++i) {
      const u16* g = bt + (size_t)(n0 + i * 32 + srow) * KP + kk * 64 + scol;
      gload16(g, &Bs[i * 2048 + w * 512]);
    }
    __syncthreads();                             // compiler drains vmcnt before barrier
#pragma unroll
    for (int kh = 0; kh < 2; ++kh) {
      bf16x8 af[4], bf[4];
#pragma unroll
      for (int i = 0; i < 4; ++i)
        af[i] = *(const bf16x8*)&As[(wr * 64 + i * 16 + l15) * 64 + kh * 32 + kgrp];
#pragma unroll
      for (int j = 0; j < 4; ++j)
        bf[j] = *(const bf16x8*)&Bs[(wc * 64 + j * 16 + l15) * 64 + kh * 32 + kgrp];
#pragma unroll
      for (int i = 0; i < 4; ++i)
#pragma unroll
        for (int j = 0; j < 4; ++j)
          acc[i][j] = __builtin_amdgcn_mfma_f32_16x16x32_bf16(af[i], bf[j], acc[i][j], 0, 0, 0);
    }
  }

  // epilogue: bias -> ELU -> BN (y = elu(v)*s + t), C/D layout: col=l&15, row=(l>>4)*4+r
  const int r0 = (l >> 4) * 4;
#pragma unroll
  for (int j = 0; j < 4; ++j) {
    const int col = n0 + wc * 64 + j * 16 + l15;
    const float bv = bias[col], sv = sb[col], tv = tb[col];
#pragma unroll
    for (int i = 0; i < 4; ++i) {
      const int row = m0 + wr * 64 + i * 16 + r0;
#pragma unroll
      for (int r = 0; r < 4; ++r) {
        float v = acc[i][j][r] + bv;
        v = v > 0.f ? v : (expf(v) - 1.f);
        out[(size_t)(row + r) * NOUT + col] = fmaf(v, sv, tv);
      }
    }
  }
}

// ---------- fallback (no workspace): fp32 vector path, correct but slow ----------
__global__ void naive_kernel(const float* __restrict__ x, const float* __restrict__ adj,
                             const float* __restrict__ W, const float* __restrict__ bias,
                             const float* __restrict__ gamma, const float* __restrict__ beta,
                             const float* __restrict__ mean, const float* __restrict__ var,
                             float* __restrict__ out) {
  __shared__ float A[NCH * NCH];
  int t = threadIdx.x;
  if (t < NCH * NCH) {
    int i = t / NCH, j = t % NCH;
    float di = 0.f, dj = 0.f;
    for (int q = 0; q < NCH; ++q) {
      di += fabsf(adj[i * NCH + q]);
      dj += fabsf(adj[j * NCH + q]);
    }
    di = fmaxf(di, 1e-8f);
    dj = fmaxf(dj, 1e-8f);
    A[t] = adj[i * NCH + j] * rsqrtf(di * dj) + (i == j ? 1.f : 0.f);
  }
  __syncthreads();
  int idx = blockIdx.x * blockDim.x + threadIdx.x;  // one (b, o) per thread
  int b = idx >> 11, o = idx & (NOUT - 1);
  const float* xb = x + (size_t)b * (NCH * FEAT);
  float sup[NCH];
#pragma unroll
  for (int j = 0; j < NCH; ++j) sup[j] = 0.f;
  for (int f = 0; f < FEAT; ++f) {
    float wv = W[(size_t)f * NOUT + o];
#pragma unroll
    for (int j = 0; j < NCH; ++j) sup[j] = fmaf(xb[j * FEAT + f], wv, sup[j]);
  }
  float sv = gamma[o] * rsqrtf(var[o] + BN_EPS);
  float tv = beta[o] - mean[o] * sv;
  float bv = bias[o];
#pragma unroll
  for (int i = 0; i < NCH; ++i) {
    float v = bv;
#pragma unroll
    for (int j = 0; j < NCH; ++j) v = fmaf(A[i * NCH + j], sup[j], v);
    v = v > 0.f ? v : (expf(v) - 1.f);
    out[((size_t)b * NCH + i) * NOUT + o] = v * sv + tv;
  }
}

extern "C" void kernel_launch(void* const* d_in, const int* in_sizes, int n_in,
                              void* d_out, int out_size, void* d_ws, size_t ws_size,
                              hipStream_t stream) {
  const float* x     = (const float*)d_in[0];
  const float* adj   = (const float*)d_in[1];
  const float* W     = (const float*)d_in[2];
  const float* bias  = (const float*)d_in[3];
  const float* gamma = (const float*)d_in[4];
  const float* beta  = (const float*)d_in[5];
  const float* mean  = (const float*)d_in[6];
  const float* var   = (const float*)d_in[7];
  float* out = (float*)d_out;

  // workspace layout
  const size_t ADJ_OFF = 0;                       // 400 B
  const size_t S_OFF   = 4096;                    // 8 KB
  const size_t T_OFF   = 12288;                   // 8 KB
  const size_t BT_OFF  = 32768;                   // 2048*6144*2 = 24 MB
  const size_t XH_OFF  = 33554432ull;             // 40960*2048*2 = 160 MB
  const size_t XL_OFF  = XH_OFF + 167772160ull;   // 160 MB
  const size_t WS_NEED = XL_OFF + 167772160ull;   // ~352 MB total

  if (ws_size >= WS_NEED) {
    char* ws = (char*)d_ws;
    float* adjn = (float*)(ws + ADJ_OFF);
    float* sbuf = (float*)(ws + S_OFF);
    float* tbuf = (float*)(ws + T_OFF);
    u16* bt = (u16*)(ws + BT_OFF);
    u16* xh = (u16*)(ws + XH_OFF);
    u16* xl = (u16*)(ws + XL_OFF);
    hipLaunchKernelGGL(prep_small_kernel, dim3(8), dim3(256), 0, stream,
                       adj, gamma, beta, mean, var, adjn, sbuf, tbuf);
    hipLaunchKernelGGL(prep_b_kernel, dim3(64, 64), dim3(32, 8), 0, stream, W, bt);
    hipLaunchKernelGGL(premix_kernel, dim3(BATCH), dim3(256), 0, stream, x, adjn, xh, xl);
    hipLaunchKernelGGL(gemm_kernel, dim3(NOUT / 128, MROWS / 128), dim3(256), 0, stream,
                       xh, xl, bt, bias, sbuf, tbuf, out);
  } else {
    hipLaunchKernelGGL(naive_kernel, dim3((BATCH * NOUT) / 256), dim3(256), 0, stream,
                       x, adj, W, bias, gamma, beta, mean, var, out);
  }
}

// Round 3
// 1640.808 us; speedup vs baseline: 1.4367x; 1.4367x over previous
//
#include <hip/hip_runtime.h>
#include <cstdint>
#include <cstddef>

// Problem constants (from reference)
#define BATCH 4096
#define NCH 10
#define FEAT 2048
#define NOUT 2048
#define MROWS (BATCH * NCH)   // 40960
#define KP 6144               // 3*FEAT for bf16x3 split GEMM
#define BN_EPS 1e-3f

using u16 = unsigned short;
typedef __attribute__((ext_vector_type(8))) short bf16x8;
typedef __attribute__((ext_vector_type(8))) unsigned short u16x8;
typedef __attribute__((ext_vector_type(4))) float f32x4;

// ---------- bf16 split helpers (manual RNE) ----------
__device__ __forceinline__ u16 f2bf(float f) {
  uint32_t u = __float_as_uint(f);
  u += 0x7FFFu + ((u >> 16) & 1u);   // round-to-nearest-even
  return (u16)(u >> 16);
}
__device__ __forceinline__ float bf2f(u16 h) {
  return __uint_as_float(((uint32_t)h) << 16);
}

// ---------- async global->LDS, 16B per lane ----------
__device__ __forceinline__ void gload16(const u16* g, u16* l) {
  __builtin_amdgcn_global_load_lds(
      (const __attribute__((address_space(1))) void*)g,
      (__attribute__((address_space(3))) void*)l, 16, 0, 0);
}

// ---------- prep: transpose W [K][N] fp32 -> Bt [N][KP] bf16 (hi, hi, lo segments) ----------
__global__ void prep_b_kernel(const float* __restrict__ W, u16* __restrict__ bt) {
  __shared__ float tile[32][33];
  int tx = threadIdx.x, ty = threadIdx.y;     // 32 x 8
  int n0 = blockIdx.x * 32, k0 = blockIdx.y * 32;
#pragma unroll
  for (int r = 0; r < 4; ++r)
    tile[ty + 8 * r][tx] = W[(size_t)(k0 + ty + 8 * r) * NOUT + n0 + tx];
  __syncthreads();
#pragma unroll
  for (int r = 0; r < 4; ++r) {
    int n = n0 + ty + 8 * r;
    int k = k0 + tx;
    float v = tile[tx][ty + 8 * r];
    u16 hi = f2bf(v);
    u16 lo = f2bf(v - bf2f(hi));
    size_t base = (size_t)n * KP;
    bt[base + k] = hi;            // seg0: paired with xm_hi
    bt[base + 2048 + k] = hi;     // seg1: paired with xm_lo
    bt[base + 4096 + k] = lo;     // seg2: paired with xm_hi
  }
}

// ---------- premix (adjn fused in): xm[b][i][f] = sum_j adjn[i][j]*x[b][j][f] -> hi/lo bf16 ----------
__global__ void __launch_bounds__(256) premix_kernel(const float* __restrict__ x,
                                                     const float* __restrict__ adj,
                                                     u16* __restrict__ xh, u16* __restrict__ xl) {
  __shared__ float A[NCH * NCH];
  int t = threadIdx.x;
  if (t < NCH * NCH) {
    int i = t / NCH, j = t % NCH;
    float di = 0.f, dj = 0.f;
#pragma unroll
    for (int q = 0; q < NCH; ++q) {
      di += fabsf(adj[i * NCH + q]);
      dj += fabsf(adj[j * NCH + q]);
    }
    di = fmaxf(di, 1e-8f);
    dj = fmaxf(dj, 1e-8f);
    A[t] = adj[i * NCH + j] * rsqrtf(di * dj) + (i == j ? 1.f : 0.f);
  }
  __syncthreads();
  int b = blockIdx.x;
  const float* xb = x + (size_t)b * (NCH * FEAT);
  u16* xhb = xh + (size_t)b * (NCH * FEAT);
  u16* xlb = xl + (size_t)b * (NCH * FEAT);
  // one 8-float chunk per thread: t in [0,256), FEAT/8 = 256
  float4 v[NCH][2];
#pragma unroll
  for (int j = 0; j < NCH; ++j) {
    const float4* xp = (const float4*)(xb + j * FEAT + t * 8);
    v[j][0] = xp[0];
    v[j][1] = xp[1];
  }
#pragma unroll
  for (int i = 0; i < NCH; ++i) {
    float o[8] = {0.f, 0.f, 0.f, 0.f, 0.f, 0.f, 0.f, 0.f};
#pragma unroll
    for (int j = 0; j < NCH; ++j) {
      float a = A[i * NCH + j];
      o[0] = fmaf(a, v[j][0].x, o[0]);
      o[1] = fmaf(a, v[j][0].y, o[1]);
      o[2] = fmaf(a, v[j][0].z, o[2]);
      o[3] = fmaf(a, v[j][0].w, o[3]);
      o[4] = fmaf(a, v[j][1].x, o[4]);
      o[5] = fmaf(a, v[j][1].y, o[5]);
      o[6] = fmaf(a, v[j][1].z, o[6]);
      o[7] = fmaf(a, v[j][1].w, o[7]);
    }
    u16x8 hv, lv;
#pragma unroll
    for (int e = 0; e < 8; ++e) {
      u16 h = f2bf(o[e]);
      hv[e] = h;
      lv[e] = f2bf(o[e] - bf2f(h));
    }
    *(u16x8*)(xhb + i * FEAT + t * 8) = hv;
    *(u16x8*)(xlb + i * FEAT + t * 8) = lv;
  }
}

// ---------- main GEMM: [40960 x 6144] x [6144 x 2048] bf16 -> fp32, fused epilogue ----------
// 128x128 tile, BK=64, 4 waves (2x2), global_load_lds w16, 2-barrier K-loop.
// + T2 both-sides XOR swizzle (linear LDS dest, pre-swizzled global source, swizzled ds_read)
// + T1 XCD chunked blockIdx swizzle (5120 % 8 == 0 -> bijective)
__global__ void __launch_bounds__(256, 3) gemm_kernel(
    const u16* __restrict__ xh, const u16* __restrict__ xl,
    const u16* __restrict__ bt, const float* __restrict__ bias,
    const float* __restrict__ gamma, const float* __restrict__ beta,
    const float* __restrict__ mean, const float* __restrict__ var,
    float* __restrict__ out) {
  __shared__ __align__(16) u16 As[128 * 64];
  __shared__ __align__(16) u16 Bs[128 * 64];
  const int tid = threadIdx.x;
  const int w = tid >> 6, l = tid & 63;
  const int wr = w >> 1, wc = w & 1;             // wave -> 64x64 quadrant
  // XCD swizzle: each XCD gets 640 contiguous (n-fast) blocks -> A-panel L2 reuse
  const int wg = blockIdx.x;
  const int swz = (wg & 7) * 640 + (wg >> 3);
  const int m0 = (swz >> 4) * 128;               // 320 M-tiles
  const int n0 = (swz & 15) * 128;               // 16 N-tiles
  // staging: lane l writes LDS linearly at (srow, chunk l&7); source col-chunk pre-XORed
  const int srow = w * 8 + (l >> 3);             // row within 32-row group
  const int scol_sw = (((l & 7) ^ ((l >> 3) & 7)) << 3);  // swizzled source col (ushorts)
  const int l15 = l & 15;

  f32x4 acc[4][4];
#pragma unroll
  for (int i = 0; i < 4; ++i)
#pragma unroll
    for (int j = 0; j < 4; ++j) acc[i][j] = (f32x4){0.f, 0.f, 0.f, 0.f};

  for (int kk = 0; kk < KP / 64; ++kk) {         // 96 K-steps
    // segment select: seg0 -> xm_hi, seg1 -> xm_lo, seg2 -> xm_hi
    const u16* Ab = (kk >= 32 && kk < 64) ? xl : xh;
    const int ak = (kk & 31) * 64;               // element offset within 2048-K array
    __syncthreads();                             // prev compute done before overwrite
#pragma unroll
    for (int i = 0; i < 4; ++i) {
      const u16* g = Ab + (size_t)(m0 + i * 32 + srow) * FEAT + ak + scol_sw;
      gload16(g, &As[i * 2048 + w * 512]);
    }
#pragma unroll
    for (int i = 0; i < 4; ++i) {
      const u16* g = bt + (size_t)(n0 + i * 32 + srow) * KP + kk * 64 + scol_sw;
      gload16(g, &Bs[i * 2048 + w * 512]);
    }
    __syncthreads();                             // drains vmcnt before barrier
#pragma unroll
    for (int kh = 0; kh < 2; ++kh) {
      bf16x8 af[4], bf[4];
#pragma unroll
      for (int i = 0; i < 4; ++i) {
        const int ra = wr * 64 + i * 16 + l15;
        const int ca = ((kh * 4 + (l >> 4)) ^ (ra & 7)) << 3;   // swizzled read col
        af[i] = *(const bf16x8*)&As[ra * 64 + ca];
      }
#pragma unroll
      for (int j = 0; j < 4; ++j) {
        const int rb = wc * 64 + j * 16 + l15;
        const int cb = ((kh * 4 + (l >> 4)) ^ (rb & 7)) << 3;
        bf[j] = *(const bf16x8*)&Bs[rb * 64 + cb];
      }
#pragma unroll
      for (int i = 0; i < 4; ++i)
#pragma unroll
        for (int j = 0; j < 4; ++j)
          acc[i][j] = __builtin_amdgcn_mfma_f32_16x16x32_bf16(af[i], bf[j], acc[i][j], 0, 0, 0);
    }
  }

  // epilogue: bias -> ELU -> BN, C/D layout: col=l&15, row=(l>>4)*4+r
  const int r0 = (l >> 4) * 4;
#pragma unroll
  for (int j = 0; j < 4; ++j) {
    const int col = n0 + wc * 64 + j * 16 + l15;
    const float sv = gamma[col] * rsqrtf(var[col] + BN_EPS);
    const float tv = beta[col] - mean[col] * sv;
    const float bv = bias[col];
#pragma unroll
    for (int i = 0; i < 4; ++i) {
      const int row = m0 + wr * 64 + i * 16 + r0;
#pragma unroll
      for (int r = 0; r < 4; ++r) {
        float v = acc[i][j][r] + bv;
        v = v > 0.f ? v : (expf(v) - 1.f);
        out[(size_t)(row + r) * NOUT + col] = fmaf(v, sv, tv);
      }
    }
  }
}

// ---------- fallback (no workspace): fp32 vector path, correct but slow ----------
__global__ void naive_kernel(const float* __restrict__ x, const float* __restrict__ adj,
                             const float* __restrict__ W, const float* __restrict__ bias,
                             const float* __restrict__ gamma, const float* __restrict__ beta,
                             const float* __restrict__ mean, const float* __restrict__ var,
                             float* __restrict__ out) {
  __shared__ float A[NCH * NCH];
  int t = threadIdx.x;
  if (t < NCH * NCH) {
    int i = t / NCH, j = t % NCH;
    float di = 0.f, dj = 0.f;
    for (int q = 0; q < NCH; ++q) {
      di += fabsf(adj[i * NCH + q]);
      dj += fabsf(adj[j * NCH + q]);
    }
    di = fmaxf(di, 1e-8f);
    dj = fmaxf(dj, 1e-8f);
    A[t] = adj[i * NCH + j] * rsqrtf(di * dj) + (i == j ? 1.f : 0.f);
  }
  __syncthreads();
  int idx = blockIdx.x * blockDim.x + threadIdx.x;  // one (b, o) per thread
  int b = idx >> 11, o = idx & (NOUT - 1);
  const float* xb = x + (size_t)b * (NCH * FEAT);
  float sup[NCH];
#pragma unroll
  for (int j = 0; j < NCH; ++j) sup[j] = 0.f;
  for (int f = 0; f < FEAT; ++f) {
    float wv = W[(size_t)f * NOUT + o];
#pragma unroll
    for (int j = 0; j < NCH; ++j) sup[j] = fmaf(xb[j * FEAT + f], wv, sup[j]);
  }
  float sv = gamma[o] * rsqrtf(var[o] + BN_EPS);
  float tv = beta[o] - mean[o] * sv;
  float bv = bias[o];
#pragma unroll
  for (int i = 0; i < NCH; ++i) {
    float v = bv;
#pragma unroll
    for (int j = 0; j < NCH; ++j) v = fmaf(A[i * NCH + j], sup[j], v);
    v = v > 0.f ? v : (expf(v) - 1.f);
    out[((size_t)b * NCH + i) * NOUT + o] = v * sv + tv;
  }
}

extern "C" void kernel_launch(void* const* d_in, const int* in_sizes, int n_in,
                              void* d_out, int out_size, void* d_ws, size_t ws_size,
                              hipStream_t stream) {
  const float* x     = (const float*)d_in[0];
  const float* adj   = (const float*)d_in[1];
  const float* W     = (const float*)d_in[2];
  const float* bias  = (const float*)d_in[3];
  const float* gamma = (const float*)d_in[4];
  const float* beta  = (const float*)d_in[5];
  const float* mean  = (const float*)d_in[6];
  const float* var   = (const float*)d_in[7];
  float* out = (float*)d_out;

  // workspace layout
  const size_t XH_OFF = 0;                        // 40960*2048*2 = 160 MB
  const size_t XL_OFF = 167772160ull;             // 160 MB
  const size_t BT_OFF = XL_OFF + 167772160ull;    // 24 MB
  const size_t WS_NEED = BT_OFF + 25165824ull;    // ~344 MB

  if (ws_size >= WS_NEED) {
    char* ws = (char*)d_ws;
    u16* xhp = (u16*)(ws + XH_OFF);
    u16* xlp = (u16*)(ws + XL_OFF);
    u16* btp = (u16*)(ws + BT_OFF);
    hipLaunchKernelGGL(prep_b_kernel, dim3(64, 64), dim3(32, 8), 0, stream, W, btp);
    hipLaunchKernelGGL(premix_kernel, dim3(BATCH), dim3(256), 0, stream, x, adj, xhp, xlp);
    hipLaunchKernelGGL(gemm_kernel, dim3((MROWS / 128) * (NOUT / 128)), dim3(256), 0, stream,
                       xhp, xlp, btp, bias, gamma, beta, mean, var, out);
  } else {
    hipLaunchKernelGGL(naive_kernel, dim3((BATCH * NOUT) / 256), dim3(256), 0, stream,
                       x, adj, W, bias, gamma, beta, mean, var, out);
  }
}